// Round 4
// baseline (155.045 us; speedup 1.0000x reference)
//
#include <hip/hip_runtime.h>

// VQ-VAE VectorQuantizer forward, MI355X (gfx950) — MFMA fp16-split, code-split x2
// inputs: d_in[0] = x (65536 x 64 f32), d_in[1] = w (1024 x 64 f32)
// out (f32 flat): [0..4194304) quantized, [4194304] loss,
//                 [4194305..+65536) indices (as float), [4259841..+65536) w.T

#define N_VEC 65536
#define D 64
#define K 1024
#define BETA 0.25f

#define OFF_Q    0
#define OFF_LOSS 4194304
#define OFF_IDX  4194305
#define OFF_WT   4259841

// ws layout (bytes): frag-ordered fp16 codebook + (-0.5*||w||^2)
#define WS_WHI  0         // 128 KB
#define WS_WLO  131072    // 128 KB
#define WS_HNEG 262144    // 4 KB

typedef _Float16 v8h __attribute__((ext_vector_type(8)));
typedef float v16f __attribute__((ext_vector_type(16)));
typedef __attribute__((address_space(3))) void lds_void_t;
typedef __attribute__((address_space(1))) const void gbl_void_t;

// ---------------- prep: LDS-tiled. grid 32 blocks, block t owns codes 32t..32t+31.
// frag order: elem e = ((t*4 + ks)*64 + l)*8 + j -> w[t*32 + (l&31)][ks*16 + (l>>5)*8 + j]
__global__ __launch_bounds__(256) void vq_prep(const float* __restrict__ w,
                                               char* __restrict__ ws,
                                               float* __restrict__ out) {
  __shared__ float s[2048];          // 32 codes x 64 depth
  const int t = blockIdx.x, tid = threadIdx.x;

  // coalesced 8 KB tile load; keep values in regs for the norm reduce
  const float4* src = (const float4*)(w + (size_t)t * 2048);
  float4 a = src[tid];               // covers code tid>>4
  float4 b = src[tid + 256];         // covers code 16 + (tid>>4)
  ((float4*)s)[tid] = a;
  ((float4*)s)[tid + 256] = b;

  float p0 = a.x * a.x + a.y * a.y + a.z * a.z + a.w * a.w;
  float p1 = b.x * b.x + b.y * b.y + b.z * b.z + b.w * b.w;
#pragma unroll
  for (int m = 1; m <= 8; m <<= 1) {   // reduce over the 16 lanes sharing a code
    p0 += __shfl_xor(p0, m, 64);
    p1 += __shfl_xor(p1, m, 64);
  }
  float* hn = (float*)(ws + WS_HNEG);
  if ((tid & 15) == 0) {
    hn[t * 32 + (tid >> 4)] = -0.5f * p0;
    hn[t * 32 + 16 + (tid >> 4)] = -0.5f * p1;
  }
  if (t == 0 && tid == 0) out[OFF_LOSS] = 0.f;   // replaces memset dispatch
  __syncthreads();

  { // frag-ordered fp16 hi/lo: thread (ks,l) writes 16 B contiguous per plane
    const int ks = tid >> 6, l = tid & 63;
    const float* r0 = s + (l & 31) * 64 + ks * 16 + ((l >> 5) << 3);
    v8h hv, lv;
#pragma unroll
    for (int j = 0; j < 8; ++j) {
      float v = r0[j];
      _Float16 h = (_Float16)v;
      hv[j] = h;
      lv[j] = (_Float16)(v - (float)h);
    }
    const size_t eoff = ((size_t)(t * 4 + ks) * 64 + l) * 16;
    *(v8h*)(ws + WS_WHI + eoff) = hv;
    *(v8h*)(ws + WS_WLO + eoff) = lv;
  }

  { // w^T: wt[d*1024 + t*32 + k] = w[(t*32+k)*64 + d]; 32 B-contiguous writes
    const int d = tid >> 2, k0 = (tid & 3) * 8;
#pragma unroll
    for (int j = 0; j < 8; ++j)
      out[OFF_WT + d * 1024 + t * 32 + k0 + j] = s[(k0 + j) * 64 + d];
  }
}

// ---------------- main: 512 blocks x 512 thr. 8 waves = 4 row-tiles x 2 code-halves.
// Each wave: 32 rows, 512 codes (8 chunks of 64). Stage 32 KB/phase (both halves).
// LDS: [0,65536) dbuf (2 x (2 halves x (8K hi + 8K lo)))  [buf0 reused as x-scratch]
//      [65536,69632) hneg, [69632,70656) merge scores, [70656,71680) merge idx
#define TPB 512
#define ROWS_PB 128
#define NPH 8

__global__ __launch_bounds__(TPB, 4) void vq_main(const float* __restrict__ x,
                                                  const float* __restrict__ w,
                                                  const char* __restrict__ ws,
                                                  float* __restrict__ out) {
  __shared__ __align__(16) char lds[71680];
  const int tid = threadIdx.x;
  const int wv = tid >> 6, ln = tid & 63;
  const int rt = wv >> 1;            // row-tile 0..3
  const int h = wv & 1;              // code-half 0..1
  const int col = ln & 31, hi = ln >> 5;
  const int rowBlk = blockIdx.x * ROWS_PB;
  const int myRow = rowBlk + rt * 32 + col;

  // ---- A fragments: x row -> fp16 hi/lo, 4 ksteps x 8 elems
  v8h ah[4], al[4];
  {
    const float* xr = x + (size_t)myRow * D + hi * 8;
#pragma unroll
    for (int ks = 0; ks < 4; ++ks) {
      float4 v0 = *(const float4*)(xr + ks * 16);
      float4 v1 = *(const float4*)(xr + ks * 16 + 4);
      float xe[8] = {v0.x, v0.y, v0.z, v0.w, v1.x, v1.y, v1.z, v1.w};
#pragma unroll
      for (int j = 0; j < 8; ++j) {
        _Float16 hh = (_Float16)xe[j];
        ah[ks][j] = hh;
        al[ks][j] = (_Float16)(xe[j] - (float)hh);
      }
    }
  }

  // ---- stage phase p's chunks (both halves) into buffer buf
  auto stage = [&](int p, int buf) {
#pragma unroll
    for (int hh = 0; hh < 2; ++hh) {
      const int c = hh * 8 + p;
      const unsigned off = (unsigned)tid * 16;       // 0..8176, uniform base + lane*16
      char* dst = lds + buf * 32768 + hh * 16384;
      __builtin_amdgcn_global_load_lds((gbl_void_t*)(ws + WS_WHI + c * 8192 + off),
                                       (lds_void_t*)(dst + off), 16, 0, 0);
      __builtin_amdgcn_global_load_lds((gbl_void_t*)(ws + WS_WLO + c * 8192 + off),
                                       (lds_void_t*)(dst + 8192 + off), 16, 0, 0);
    }
  };

  v16f best;
  int bidx[16];
#pragma unroll
  for (int r = 0; r < 16; ++r) { best[r] = -3.0e38f; bidx[r] = 0; }

  stage(0, 0);
  if (tid < 256)   // hneg 4 KB (waves 0-3 full -> uniform base + lane*16)
    __builtin_amdgcn_global_load_lds((gbl_void_t*)(ws + WS_HNEG + tid * 16),
                                     (lds_void_t*)(lds + 65536 + tid * 16), 16, 0, 0);
  asm volatile("s_waitcnt vmcnt(0)" ::: "memory");
  __syncthreads();

  const float* hn_l = (const float*)(lds + 65536);

  for (int p = 0; p < NPH; ++p) {
    const int buf = p & 1;
    if (p + 1 < NPH) stage(p + 1, buf ^ 1);
    const char* wb = lds + buf * 32768 + h * 16384;
    const int c = h * 8 + p;

    const float h0 = hn_l[c * 64 + col];
    const float h1 = hn_l[c * 64 + 32 + col];
    v16f aA, aB;
#pragma unroll
    for (int r = 0; r < 16; ++r) { aA[r] = h0; aB[r] = h1; }

#pragma unroll
    for (int ks = 0; ks < 4; ++ks) {
      v8h bhA = *(const v8h*)(wb + ks * 1024 + ln * 16);
      v8h blA = *(const v8h*)(wb + 8192 + ks * 1024 + ln * 16);
      v8h bhB = *(const v8h*)(wb + 4096 + ks * 1024 + ln * 16);
      v8h blB = *(const v8h*)(wb + 8192 + 4096 + ks * 1024 + ln * 16);
      aA = __builtin_amdgcn_mfma_f32_32x32x16_f16(ah[ks], bhA, aA, 0, 0, 0);
      aB = __builtin_amdgcn_mfma_f32_32x32x16_f16(ah[ks], bhB, aB, 0, 0, 0);
      aA = __builtin_amdgcn_mfma_f32_32x32x16_f16(al[ks], bhA, aA, 0, 0, 0);
      aB = __builtin_amdgcn_mfma_f32_32x32x16_f16(al[ks], bhB, aB, 0, 0, 0);
      aA = __builtin_amdgcn_mfma_f32_32x32x16_f16(ah[ks], blA, aA, 0, 0, 0);
      aB = __builtin_amdgcn_mfma_f32_32x32x16_f16(ah[ks], blB, aB, 0, 0, 0);
    }

    const int kgA = c * 64 + col;     // ascending k order => strict > keeps first max
    const int kgB = c * 64 + 32 + col;
#pragma unroll
    for (int r = 0; r < 16; ++r) {
      if (aA[r] > best[r]) { best[r] = aA[r]; bidx[r] = kgA; }
      if (aB[r] > best[r]) { best[r] = aB[r]; bidx[r] = kgB; }
    }

    asm volatile("s_waitcnt vmcnt(0)" ::: "memory");
    __syncthreads();
  }

  // ---- cross-lane argmax reduce over the 32 codeword-cols
#pragma unroll
  for (int m = 1; m <= 16; m <<= 1) {
#pragma unroll
    for (int r = 0; r < 16; ++r) {
      float ov = __shfl_xor(best[r], m, 64);
      int oi = __shfl_xor(bidx[r], m, 64);
      if (ov > best[r] || (ov == best[r] && oi < bidx[r])) { best[r] = ov; bidx[r] = oi; }
    }
  }

  // ---- publish per-row winners per half; reconstruct x into LDS (swizzled)
  float* resS = (float*)(lds + 69632);
  int*   resI = (int*)(lds + 70656);
  if (col == 0) {
#pragma unroll
    for (int r = 0; r < 16; ++r) {
      int row = (r & 3) + 8 * (r >> 2) + 4 * hi;    // C/D row mapping
      int row128 = rt * 32 + row;
      resS[row128 * 2 + h] = best[r];
      resI[row128 * 2 + h] = bidx[r];
    }
  }
  if (h == 0) {   // x-scratch into [0,32768) — buffer 0 is dead after the loop
    const int row = rt * 32 + col;
    const unsigned swz = (unsigned)((row & 7) << 4);
#pragma unroll
    for (int ks = 0; ks < 4; ++ks) {
      float4 q0 = make_float4((float)ah[ks][0] + (float)al[ks][0],
                              (float)ah[ks][1] + (float)al[ks][1],
                              (float)ah[ks][2] + (float)al[ks][2],
                              (float)ah[ks][3] + (float)al[ks][3]);
      float4 q1 = make_float4((float)ah[ks][4] + (float)al[ks][4],
                              (float)ah[ks][5] + (float)al[ks][5],
                              (float)ah[ks][6] + (float)al[ks][6],
                              (float)ah[ks][7] + (float)al[ks][7]);
      unsigned b = (unsigned)(row * 256 + (ks * 16 + hi * 8) * 4);
      *(float4*)((char*)lds + (b ^ swz)) = q0;
      *(float4*)((char*)lds + ((b + 16) ^ swz)) = q1;
    }
  }
  __syncthreads();

  // ---- merged epilogue: 4 threads per row (16 floats each)
  const int row128 = tid >> 2, part = tid & 3;
  const int grow = rowBlk + row128;
  const float s0 = resS[row128 * 2], s1v = resS[row128 * 2 + 1];
  const int bi = (s1v > s0) ? resI[row128 * 2 + 1] : resI[row128 * 2]; // half0 wins ties (smaller idx)
  if (part == 0) out[OFF_IDX + grow] = (float)bi;

  const float4* qsrc = (const float4*)(w + (size_t)bi * D + part * 16);
  float4* qdst = (float4*)(out + OFF_Q + (size_t)grow * D + part * 16);
  const unsigned eswz = (unsigned)((row128 & 7) << 4);
  float sse = 0.f;
#pragma unroll
  for (int i = 0; i < 4; ++i) {
    float4 q = qsrc[i];
    qdst[i] = q;
    unsigned bb = (unsigned)(row128 * 256 + part * 64 + i * 16);
    float4 xv4 = *(const float4*)((const char*)lds + (bb ^ eswz));
    float d0 = q.x - xv4.x, d1 = q.y - xv4.y;
    float d2 = q.z - xv4.z, d3 = q.w - xv4.w;
    sse += d0 * d0 + d1 * d1 + d2 * d2 + d3 * d3;
  }
#pragma unroll
  for (int off = 32; off >= 1; off >>= 1) sse += __shfl_xor(sse, off, 64);
  if (ln == 0) atomicAdd(out + OFF_LOSS, sse * (BETA / (float)(N_VEC * D)));
}

extern "C" void kernel_launch(void* const* d_in, const int* in_sizes, int n_in,
                              void* d_out, int out_size, void* d_ws, size_t ws_size,
                              hipStream_t stream) {
  const float* x = (const float*)d_in[0];
  const float* w = (const float*)d_in[1];
  float* out = (float*)d_out;
  char* ws = (char*)d_ws;

  vq_prep<<<32, 256, 0, stream>>>(w, ws, out);
  vq_main<<<N_VEC / ROWS_PB, TPB, 0, stream>>>(x, w, ws, out);
}